// Round 1
// baseline (187.390 us; speedup 1.0000x reference)
//
#include <hip/hip_runtime.h>

typedef _Float16 half8 __attribute__((ext_vector_type(8)));
typedef float f32x4 __attribute__((ext_vector_type(4)));
typedef float f32x2 __attribute__((ext_vector_type(2)));

#define NB    8
#define QLEN  512
#define NS    64
#define LS    128
#define EDIM  256
#define QT    64      // q rows per block
#define WQ    16      // q rows per wave
#define NWAVE 4
#define PSTRIDE 132   // dwords per P row (128 + 4 pad)

__global__ __launch_bounds__(256, 3)
void DotAttn_20083267076209_kernel(const float* __restrict__ qg,
                                   const float* __restrict__ kg,
                                   const float* __restrict__ vg,
                                   const int*   __restrict__ maskg,
                                   float*       __restrict__ outg)
{
    // kvbuf: union of K-chunk [32][256] fp16 (swizzled) and V^T-chunk [256][32] fp16 (swizzled)
    __shared__ __align__(16) unsigned char kvbuf[16384];
    __shared__ __align__(16) float pbuf[NWAVE * WQ * PSTRIDE];   // 33792 B
    __shared__ int maskbuf[LS];

    const int tid  = threadIdx.x;
    const int w    = tid >> 6;     // wave id 0..3
    const int lane = tid & 63;
    const int c    = lane & 15;    // MFMA row/col lane index
    const int g    = lane >> 4;    // MFMA k-group

    const int bid = blockIdx.x;
    const int qt  = bid & 7;               // 8 q-tiles of 64
    const int s   = (bid >> 3) & (NS - 1);
    const int b   = bid >> 9;

    const float* qbase = qg + ((size_t)b * QLEN + (size_t)qt * QT + (size_t)w * WQ) * EDIM;
    const float* kbase = kg + (size_t)(b * NS + s) * LS * EDIM;
    const float* vbase = vg + (size_t)(b * NS + s) * LS * EDIM;

    if (tid < LS) maskbuf[tid] = maskg[(b * NS + s) * LS + tid];

    // ---- Q A-fragments: global fp32 -> fp16 regs. A[row=c][k = ks*32 + g*8 + j] ----
    half8 qf[8];
#pragma unroll
    for (int ks = 0; ks < 8; ++ks) {
        const float* p = qbase + (size_t)c * EDIM + ks * 32 + g * 8;
        f32x4 a = *(const f32x4*)p;
        f32x4 d = *(const f32x4*)(p + 4);
        half8 h;
        h[0]=(_Float16)a[0]; h[1]=(_Float16)a[1]; h[2]=(_Float16)a[2]; h[3]=(_Float16)a[3];
        h[4]=(_Float16)d[0]; h[5]=(_Float16)d[1]; h[6]=(_Float16)d[2]; h[7]=(_Float16)d[3];
        qf[ks] = h;
    }

    // ---- S = Q K^T : per wave 16 q-rows x 128 l, K staged in 32-l chunks ----
    f32x4 sacc[8];
#pragma unroll
    for (int t = 0; t < 8; ++t) sacc[t] = (f32x4){0.f, 0.f, 0.f, 0.f};

#pragma unroll
    for (int lt = 0; lt < 4; ++lt) {
        if (lt) __syncthreads();
        // stage K rows [lt*32, lt*32+32): 256 thr x 32 fp32 each, coalesced, XOR-swizzled
#pragma unroll
        for (int it = 0; it < 4; ++it) {
            int f  = it * 2048 + tid * 8;
            int r  = f >> 8;          // 0..31
            int e0 = f & 255;
            const float* src = kbase + (size_t)(lt * 32 + r) * EDIM + e0;
            f32x4 a = *(const f32x4*)src;
            f32x4 d = *(const f32x4*)(src + 4);
            half8 h;
            h[0]=(_Float16)a[0]; h[1]=(_Float16)a[1]; h[2]=(_Float16)a[2]; h[3]=(_Float16)a[3];
            h[4]=(_Float16)d[0]; h[5]=(_Float16)d[1]; h[6]=(_Float16)d[2]; h[7]=(_Float16)d[3];
            int byte = (r * 512 + e0 * 2) ^ ((r & 7) << 4);
            *(half8*)(kvbuf + byte) = h;
        }
        __syncthreads();
#pragma unroll
        for (int lb = 0; lb < 2; ++lb) {
            int row = lb * 16 + c;              // l within chunk
            int sw  = (row & 7) << 4;
#pragma unroll
            for (int ks = 0; ks < 8; ++ks) {
                int byte = (row * 512 + ks * 64 + g * 16) ^ sw;
                half8 bf = *(const half8*)(kvbuf + byte);
                sacc[lt * 2 + lb] =
                    __builtin_amdgcn_mfma_f32_16x16x32_f16(qf[ks], bf, sacc[lt * 2 + lb], 0, 0, 0);
            }
        }
    }

    // ---- mask + softmax over l (row q = w*16 + 4g + r, col l = t*16 + c) ----
#pragma unroll
    for (int t = 0; t < 8; ++t) {
        if (maskbuf[t * 16 + c] == 0) {
            sacc[t][0] = -1e30f; sacc[t][1] = -1e30f;
            sacc[t][2] = -1e30f; sacc[t][3] = -1e30f;
        }
    }
#pragma unroll
    for (int r = 0; r < 4; ++r) {
        float m = sacc[0][r];
#pragma unroll
        for (int t = 1; t < 8; ++t) m = fmaxf(m, sacc[t][r]);
        m = fmaxf(m, __shfl_xor(m, 1, 64));
        m = fmaxf(m, __shfl_xor(m, 2, 64));
        m = fmaxf(m, __shfl_xor(m, 4, 64));
        m = fmaxf(m, __shfl_xor(m, 8, 64));
        float sum = 0.f;
#pragma unroll
        for (int t = 0; t < 8; ++t) {
            float p = __expf(sacc[t][r] - m);
            sacc[t][r] = p;
            sum += p;
        }
        sum += __shfl_xor(sum, 1, 64);
        sum += __shfl_xor(sum, 2, 64);
        sum += __shfl_xor(sum, 4, 64);
        sum += __shfl_xor(sum, 8, 64);
        float inv = 1.f / sum;
#pragma unroll
        for (int t = 0; t < 8; ++t) sacc[t][r] *= inv;
    }

    // ---- P -> LDS (per-wave region, fp32, padded stride) ----
    {
        float* prow = pbuf + (size_t)w * WQ * PSTRIDE;
#pragma unroll
        for (int r = 0; r < 4; ++r) {
            int qr = 4 * g + r;
#pragma unroll
            for (int t = 0; t < 8; ++t)
                prow[qr * PSTRIDE + t * 16 + c] = sacc[t][r];
        }
    }
    __syncthreads();   // P visible + kvbuf free for V staging

    // ---- O = P V : V^T staged per 32-l chunk ----
    f32x4 oacc[16];
#pragma unroll
    for (int et = 0; et < 16; ++et) oacc[et] = (f32x4){0.f, 0.f, 0.f, 0.f};

    const int ehalf = tid & 127;   // e-pair index: rows 2*ehalf, 2*ehalf+1
    const int lh    = tid >> 7;    // l-half 0/1

#pragma unroll
    for (int lt = 0; lt < 4; ++lt) {
        if (lt) __syncthreads();
        // stage V^T chunk: coalesced float2 global reads, swizzled transposed LDS writes
#pragma unroll
        for (int jj = 0; jj < 2; ++jj) {
            int lbase = lt * 32 + lh * 16 + jj * 8;
            half8 h0, h1;
#pragma unroll
            for (int j = 0; j < 8; ++j) {
                f32x2 t2 = *(const f32x2*)(vbase + (size_t)(lbase + j) * EDIM + 2 * ehalf);
                h0[j] = (_Float16)t2[0];
                h1[j] = (_Float16)t2[1];
            }
            int u  = lh * 2 + jj;              // 16B unit within a 64B V^T row
            int sw = (ehalf & 7) << 4;         // ((e>>1)&7)<<4, same for the pair
            int e0 = 2 * ehalf;
            *(half8*)(kvbuf + (((e0    ) * 64 + u * 16) ^ sw)) = h0;
            *(half8*)(kvbuf + (((e0 + 1) * 64 + u * 16) ^ sw)) = h1;
        }
        __syncthreads();
        // A-frag: P[q=c][l = lt*32 + g*8 + j]
        const float* pr = pbuf + ((size_t)w * WQ + c) * PSTRIDE + lt * 32 + g * 8;
        f32x4 a = *(const f32x4*)pr;
        f32x4 d = *(const f32x4*)(pr + 4);
        half8 af;
        af[0]=(_Float16)a[0]; af[1]=(_Float16)a[1]; af[2]=(_Float16)a[2]; af[3]=(_Float16)a[3];
        af[4]=(_Float16)d[0]; af[5]=(_Float16)d[1]; af[6]=(_Float16)d[2]; af[7]=(_Float16)d[3];
#pragma unroll
        for (int et = 0; et < 16; ++et) {
            int erow = et * 16 + c;
            int byte = (erow * 64 + g * 16) ^ (((erow >> 1) & 7) << 4);
            half8 bf = *(const half8*)(kvbuf + byte);
            oacc[et] = __builtin_amdgcn_mfma_f32_16x16x32_f16(af, bf, oacc[et], 0, 0, 0);
        }
    }

    // ---- epilogue: out[b][q][s][e], q = qt*64 + w*16 + 4g + r, e = et*16 + c ----
    float* ob = outg + (((size_t)b * QLEN + (size_t)qt * QT + w * WQ + 4 * g) * NS + s) * EDIM + c;
#pragma unroll
    for (int et = 0; et < 16; ++et) {
#pragma unroll
        for (int r = 0; r < 4; ++r)
            ob[(size_t)r * NS * EDIM + et * 16] = oacc[et][r];
    }
}

extern "C" void kernel_launch(void* const* d_in, const int* in_sizes, int n_in,
                              void* d_out, int out_size, void* d_ws, size_t ws_size,
                              hipStream_t stream) {
    const float* q    = (const float*)d_in[0];
    const float* k    = (const float*)d_in[1];
    const float* v    = (const float*)d_in[2];
    const int*   mask = (const int*)d_in[3];
    float* out = (float*)d_out;
    dim3 grid(NB * NS * (QLEN / QT));   // 8 * 64 * 8 = 4096
    dim3 block(256);
    hipLaunchKernelGGL(DotAttn_20083267076209_kernel, grid, block, 0, stream,
                       q, k, v, mask, out);
}